// Round 1
// baseline (167.187 us; speedup 1.0000x reference)
//
#include <hip/hip_runtime.h>
#include <math.h>

#define NB 64
#define NN 512
#define ND 128

// workspace layout (floats)
#define KV_OFF   0
#define QK_OFF   (NB*NN*ND)           // 64*512*128
#define QSUM_OFF (QK_OFF + NB*NN)
#define WS_FLOATS (QSUM_OFF + NB*ND)

// Kernel 1: q/k projections for a 64-row tile of one batch.
// Writes k rows, qk[b,n] = q.k (raw, mask applied later), and atomically
// accumulates q_sum[b,d] = sum_n mask*q.
__global__ __launch_bounds__(256) void proj_kernel(
    const float* __restrict__ aq,     // [B][N][D]
    const float* __restrict__ mask,   // [B][N]
    const float* __restrict__ Wq,     // [D][ND]
    const float* __restrict__ bq,     // [ND]
    const float* __restrict__ Wk,     // [D][ND]
    const float* __restrict__ bk,     // [ND]
    float* __restrict__ kv,           // [B][N][ND]
    float* __restrict__ qk,           // [B][N]
    float* __restrict__ qsum)         // [B][ND]
{
    __shared__ float a_lds[64][128];      // 32 KB input tile
    __shared__ float qs_part[4][128];
    __shared__ float mask_lds[64];

    const int b  = blockIdx.x >> 3;
    const int n0 = (blockIdx.x & 7) * 64;
    const int t  = threadIdx.x;

    {   // coalesced float4 tile load: 2048 float4s / 256 threads
        const float4* src = (const float4*)(aq + ((size_t)b*NN + n0)*ND);
        float4* dst = (float4*)(&a_lds[0][0]);
        #pragma unroll
        for (int i = 0; i < 8; i++) dst[t + 256*i] = src[t + 256*i];
    }
    if (t < 64) mask_lds[t] = mask[b*NN + n0 + t];
    __syncthreads();

    const int tx = t & 63;        // cols tx and tx+64
    const int ty = t >> 6;        // rows ty*16 .. ty*16+15
    const int c0 = tx, c1 = tx + 64;
    const int r0 = ty * 16;

    float accq0[16], accq1[16], acck0[16], acck1[16];
    {
        const float bqv0 = bq[c0], bqv1 = bq[c1];
        const float bkv0 = bk[c0], bkv1 = bk[c1];
        #pragma unroll
        for (int r = 0; r < 16; r++) {
            accq0[r] = bqv0; accq1[r] = bqv1;
            acck0[r] = bkv0; acck1[r] = bkv1;
        }
    }

    for (int kk = 0; kk < 128; kk += 4) {
        float wq0[4], wq1[4], wk0[4], wk1[4];
        #pragma unroll
        for (int i = 0; i < 4; i++) {
            wq0[i] = Wq[(kk+i)*ND + c0];
            wq1[i] = Wq[(kk+i)*ND + c1];
            wk0[i] = Wk[(kk+i)*ND + c0];
            wk1[i] = Wk[(kk+i)*ND + c1];
        }
        #pragma unroll
        for (int r = 0; r < 16; r++) {
            const float4 a4 = *(const float4*)&a_lds[r0 + r][kk];  // wave-broadcast
            accq0[r] += a4.x*wq0[0] + a4.y*wq0[1] + a4.z*wq0[2] + a4.w*wq0[3];
            accq1[r] += a4.x*wq1[0] + a4.y*wq1[1] + a4.z*wq1[2] + a4.w*wq1[3];
            acck0[r] += a4.x*wk0[0] + a4.y*wk0[1] + a4.z*wk0[2] + a4.w*wk0[3];
            acck1[r] += a4.x*wk1[0] + a4.y*wk1[1] + a4.z*wk1[2] + a4.w*wk1[3];
        }
    }

    // store k rows (coalesced across lanes)
    #pragma unroll
    for (int r = 0; r < 16; r++) {
        const size_t row = (size_t)b*NN + n0 + r0 + r;
        kv[row*ND + c0] = acck0[r];
        kv[row*ND + c1] = acck1[r];
    }

    // qk[b,n] = q.k : per-row wave reduction (each wave owns its 16 rows)
    #pragma unroll
    for (int r = 0; r < 16; r++) {
        float p = accq0[r]*acck0[r] + accq1[r]*acck1[r];
        #pragma unroll
        for (int off = 32; off; off >>= 1) p += __shfl_down(p, off);
        if (tx == 0) qk[(size_t)b*NN + n0 + r0 + r] = p;
    }

    // q_sum partial: sum_r mask*q over this block's 64 rows, then atomic
    {
        float s0 = 0.f, s1 = 0.f;
        #pragma unroll
        for (int r = 0; r < 16; r++) {
            const float m = mask_lds[r0 + r];
            s0 += m * accq0[r];
            s1 += m * accq1[r];
        }
        qs_part[ty][c0] = s0;
        qs_part[ty][c1] = s1;
    }
    __syncthreads();
    if (t < 128) {
        const float s = qs_part[0][t] + qs_part[1][t] + qs_part[2][t] + qs_part[3][t];
        atomicAdd(&qsum[b*ND + t], s);
    }
}

// Kernel 2: one block per batch. agg -> normalize -> masked softmax -> attn,
// then context = sum_n e_n * k[n,:] / Z.
__global__ __launch_bounds__(512) void attn_kernel(
    const float* __restrict__ mask,
    const float* __restrict__ kv,
    const float* __restrict__ qk,
    const float* __restrict__ qsum,
    float* __restrict__ out_attn,   // [B][N]
    float* __restrict__ out_ctx)    // [B][ND]
{
    __shared__ float qs[128];
    __shared__ float agg_s[512];
    __shared__ float red[16];
    __shared__ float bc[2];
    __shared__ float ctx_part[4][128];

    const int b = blockIdx.x;
    const int t = threadIdx.x;
    const int lane = t & 63, wave = t >> 6;

    if (t < 128) qs[t] = qsum[b*ND + t];
    __syncthreads();

    // Phase A: agg[n] = mask * (k[n].q_sum - qk[n]); one wave per n
    for (int i = 0; i < 64; i++) {
        const int n = wave*64 + i;
        const float* krow = kv + ((size_t)b*NN + n)*ND;
        float p = krow[lane]*qs[lane] + krow[lane+64]*qs[lane+64];
        #pragma unroll
        for (int off = 32; off; off >>= 1) p += __shfl_down(p, off);
        if (lane == 0)
            agg_s[n] = mask[b*NN + n] * (p - qk[(size_t)b*NN + n]);
    }
    __syncthreads();

    // norm + masked max
    const float v  = agg_s[t];
    const bool um  = mask[b*NN + t] != 0.0f;
    float sq = v * v;
    float mx = um ? v : -3.0e38f;
    #pragma unroll
    for (int off = 32; off; off >>= 1) {
        sq += __shfl_down(sq, off);
        mx = fmaxf(mx, __shfl_down(mx, off));
    }
    if (lane == 0) { red[wave] = sq; red[8 + wave] = mx; }
    __syncthreads();
    if (t == 0) {
        float s = 0.f, m = -3.0e38f;
        #pragma unroll
        for (int w = 0; w < 8; w++) { s += red[w]; m = fmaxf(m, red[8 + w]); }
        bc[0] = sqrtf(s);
        bc[1] = m;
    }
    __syncthreads();
    const float nrm = bc[0];
    const float M   = bc[1];

    // masked exp (masked lanes are exactly 0, matching exp(-1e9) underflow)
    const float e = um ? expf((v - M) / nrm) : 0.0f;
    agg_s[t] = e;                 // reuse as e storage (own slot only)
    float z = e;
    #pragma unroll
    for (int off = 32; off; off >>= 1) z += __shfl_down(z, off);
    if (lane == 0) red[wave] = z;
    __syncthreads();
    if (t == 0) {
        float s = 0.f;
        #pragma unroll
        for (int w = 0; w < 8; w++) s += red[w];
        bc[0] = s;
    }
    __syncthreads();
    const float Z = bc[0];
    out_attn[(size_t)b*NN + t] = e / Z;

    // Phase B: context
    const int d = t & 127, g = t >> 7;
    float acc = 0.f;
    for (int n = g; n < NN; n += 4)
        acc += agg_s[n] * kv[((size_t)b*NN + n)*ND + d];   // coalesced
    ctx_part[g][d] = acc;
    __syncthreads();
    if (t < 128)
        out_ctx[(size_t)b*ND + t] =
            (ctx_part[0][t] + ctx_part[1][t] + ctx_part[2][t] + ctx_part[3][t]) / Z;
}

extern "C" void kernel_launch(void* const* d_in, const int* in_sizes, int n_in,
                              void* d_out, int out_size, void* d_ws, size_t ws_size,
                              hipStream_t stream)
{
    const float* aq   = (const float*)d_in[0];
    const float* mask = (const float*)d_in[1];
    const float* Wq   = (const float*)d_in[2];
    const float* bq   = (const float*)d_in[3];
    const float* Wk   = (const float*)d_in[4];
    const float* bk   = (const float*)d_in[5];

    float* ws   = (float*)d_ws;
    float* kv   = ws + KV_OFF;
    float* qk   = ws + QK_OFF;
    float* qsum = ws + QSUM_OFF;

    float* out_attn = (float*)d_out;
    float* out_ctx  = (float*)d_out + NB*NN;

    hipMemsetAsync(qsum, 0, NB*ND*sizeof(float), stream);
    proj_kernel<<<dim3(NB*8), dim3(256), 0, stream>>>(aq, mask, Wq, bq, Wk, bk, kv, qk, qsum);
    attn_kernel<<<dim3(NB), dim3(512), 0, stream>>>(mask, kv, qk, qsum, out_attn, out_ctx);
}

// Round 2
// 139.407 us; speedup vs baseline: 1.1993x; 1.1993x over previous
//
#include <hip/hip_runtime.h>
#include <math.h>

#define NB 64
#define NN 512
#define ND 128

typedef __attribute__((ext_vector_type(8))) short short8;
typedef __attribute__((ext_vector_type(4))) float f32x4;

// workspace layout (floats)
#define KV_OFF    0
#define QK_OFF    (NB*NN*ND)
#define AGG_OFF   (QK_OFF + NB*NN)
#define WT_OFF    (AGG_OFF + NB*NN)        // 256*128 bf16 = 16384 floats
#define QSUM_OFF  (WT_OFF + 16384)
#define NORM2_OFF (QSUM_OFF + NB*ND)
#define MAXU_OFF  (NORM2_OFF + NB)

__device__ inline unsigned short f2bf(float x) {
    unsigned int u = __float_as_uint(x);
    return (unsigned short)((u + 0x7FFFu + ((u >> 16) & 1u)) >> 16);
}

// K0: Wt[c][k] = (c<128 ? Wq : Wk)[k][c%128], bf16, B-fragment friendly
__global__ __launch_bounds__(256) void conv_w(
    const float* __restrict__ Wq, const float* __restrict__ Wk,
    unsigned short* __restrict__ Wt)
{
    const int idx = blockIdx.x * 256 + threadIdx.x;   // 0..32767
    const int c = idx >> 7, k = idx & 127;
    const float v = (c < ND) ? Wq[k*ND + c] : Wk[k*ND + (c - ND)];
    Wt[c*ND + k] = f2bf(v);
}

// K1: bf16 MFMA projection. Per block: 128 rows x (128 q-cols + 128 k-cols).
// Emits kv (k proj, fp32), qk[b,n] = q.k, qsum[b,d] += sum_n mask*q.
__global__ __launch_bounds__(256, 1) void proj_mfma(
    const float* __restrict__ aq, const float* __restrict__ mask,
    const unsigned short* __restrict__ Wt,
    const float* __restrict__ bq, const float* __restrict__ bk,
    float* __restrict__ kv, float* __restrict__ qk, float* __restrict__ qsum)
{
    __shared__ __align__(16) unsigned short a_lds[128][136];  // pitch 136: 2-way-free banks
    __shared__ float mask_lds[128];
    __shared__ float qk_part[4][128];

    const int b    = blockIdx.x >> 2;
    const int m0   = (blockIdx.x & 3) << 7;
    const int t    = threadIdx.x;
    const int w    = t >> 6, lane = t & 63;
    const int quad = lane >> 4, l16 = lane & 15;

    // stage aq tile fp32 -> bf16 LDS (coalesced float4 reads)
    {
        const float4* src = (const float4*)(aq + ((size_t)b*NN + m0)*ND);
        #pragma unroll
        for (int i = 0; i < 16; i++) {
            const int idx = t + 256*i;
            const int row = idx >> 5, c4 = idx & 31;
            const float4 v = src[idx];
            ushort4 o;
            o.x = f2bf(v.x); o.y = f2bf(v.y); o.z = f2bf(v.z); o.w = f2bf(v.w);
            *(ushort4*)&a_lds[row][c4*4] = o;
        }
        if (t < 128) mask_lds[t] = mask[b*NN + m0 + t];
    }

    // B fragments in registers: nt 0,1 = q cols [w*32, w*32+32); nt 2,3 = k cols same range
    short8 bfr[4][4];
    #pragma unroll
    for (int nt = 0; nt < 4; nt++) {
        const int col = (nt < 2) ? (w*32 + nt*16 + l16)
                                 : (ND + w*32 + (nt-2)*16 + l16);
        #pragma unroll
        for (int kc = 0; kc < 4; kc++)
            bfr[nt][kc] = *(const short8*)(Wt + col*ND + kc*32 + quad*8);
    }

    __syncthreads();

    f32x4 acc[8][4];
    #pragma unroll
    for (int m = 0; m < 8; m++)
        #pragma unroll
        for (int nt = 0; nt < 4; nt++)
            acc[m][nt] = (f32x4){0.f, 0.f, 0.f, 0.f};

    #pragma unroll
    for (int m = 0; m < 8; m++) {
        short8 afr[4];
        #pragma unroll
        for (int kc = 0; kc < 4; kc++)
            afr[kc] = *(const short8*)&a_lds[m*16 + l16][kc*32 + quad*8];
        #pragma unroll
        for (int nt = 0; nt < 4; nt++)
            #pragma unroll
            for (int kc = 0; kc < 4; kc++)
                acc[m][nt] = __builtin_amdgcn_mfma_f32_16x16x32_bf16(
                    afr[kc], bfr[nt][kc], acc[m][nt], 0, 0, 0);
    }

    // bias
    float bv[4];
    #pragma unroll
    for (int nt = 0; nt < 2; nt++) bv[nt] = bq[w*32 + nt*16 + l16];
    #pragma unroll
    for (int nt = 2; nt < 4; nt++) bv[nt] = bk[w*32 + (nt-2)*16 + l16];
    #pragma unroll
    for (int m = 0; m < 8; m++)
        #pragma unroll
        for (int nt = 0; nt < 4; nt++)
            #pragma unroll
            for (int r = 0; r < 4; r++)
                acc[m][nt][r] += bv[nt];

    // store k rows (C layout: row = m*16 + quad*4 + r, col = base + l16)
    #pragma unroll
    for (int m = 0; m < 8; m++)
        #pragma unroll
        for (int r = 0; r < 4; r++) {
            const size_t row = (size_t)b*NN + m0 + m*16 + quad*4 + r;
            kv[row*ND + w*32 + l16]      = acc[m][2][r];
            kv[row*ND + w*32 + 16 + l16] = acc[m][3][r];
        }

    // qk partial: sum over this wave's 32 d-cols, butterfly over the 16-lane col group
    #pragma unroll
    for (int m = 0; m < 8; m++) {
        float p[4];
        #pragma unroll
        for (int r = 0; r < 4; r++)
            p[r] = acc[m][0][r]*acc[m][2][r] + acc[m][1][r]*acc[m][3][r];
        #pragma unroll
        for (int off = 1; off <= 8; off <<= 1)
            #pragma unroll
            for (int r = 0; r < 4; r++)
                p[r] += __shfl_xor(p[r], off);
        if (l16 == 0)
            #pragma unroll
            for (int r = 0; r < 4; r++)
                qk_part[w][m*16 + quad*4 + r] = p[r];
    }

    // qsum partial: reduce over rows (mask per row), butterfly over quads
    {
        float s0 = 0.f, s1 = 0.f;
        #pragma unroll
        for (int m = 0; m < 8; m++)
            #pragma unroll
            for (int r = 0; r < 4; r++) {
                const float mk = mask_lds[m*16 + quad*4 + r];
                s0 += mk * acc[m][0][r];
                s1 += mk * acc[m][1][r];
            }
        s0 += __shfl_xor(s0, 16); s0 += __shfl_xor(s0, 32);
        s1 += __shfl_xor(s1, 16); s1 += __shfl_xor(s1, 32);
        if (quad == 0) {
            atomicAdd(&qsum[b*ND + w*32 + l16],      s0);
            atomicAdd(&qsum[b*ND + w*32 + 16 + l16], s1);
        }
    }

    __syncthreads();
    if (t < 128)
        qk[(size_t)b*NN + m0 + t] =
            qk_part[0][t] + qk_part[1][t] + qk_part[2][t] + qk_part[3][t];
}

// K2a: agg[b,n] = mask*(k[n].qsum - qk[n]); per-wave partial norm2 + encoded max
__global__ __launch_bounds__(256) void agg_kernel(
    const float* __restrict__ mask, const float* __restrict__ kv,
    const float* __restrict__ qk, const float* __restrict__ qsum,
    float* __restrict__ agg, float* __restrict__ norm2,
    unsigned int* __restrict__ maxu)
{
    __shared__ float qs[128];
    const int b  = blockIdx.x >> 3;
    const int r0 = (blockIdx.x & 7) << 6;
    const int t = threadIdx.x, w = t >> 6, lane = t & 63;

    if (t < 128) qs[t] = qsum[b*ND + t];
    __syncthreads();

    const float q0 = qs[2*lane], q1 = qs[2*lane + 1];

    float ns = 0.f;
    unsigned int mx = 0u;
    for (int i = 0; i < 16; i++) {
        const int n = r0 + w*16 + i;
        const float2 kvv = *(const float2*)(kv + ((size_t)b*NN + n)*ND + 2*lane);
        float p = kvv.x*q0 + kvv.y*q1;
        #pragma unroll
        for (int off = 1; off <= 32; off <<= 1) p += __shfl_xor(p, off);
        if (lane == 0) {
            const float mk = mask[b*NN + n];
            const float ag = mk * (p - qk[(size_t)b*NN + n]);
            agg[(size_t)b*NN + n] = ag;
            ns += ag * ag;
            if (mk != 0.f) {
                const unsigned int ub = __float_as_uint(ag);
                const unsigned int enc = (ub & 0x80000000u) ? ~ub : (ub | 0x80000000u);
                mx = mx > enc ? mx : enc;
            }
        }
    }
    if (lane == 0) {
        atomicAdd(&norm2[b], ns);
        atomicMax(&maxu[b], mx);
    }
}

// K2b: softmax over atoms + context
__global__ __launch_bounds__(512) void attn_kernel(
    const float* __restrict__ mask, const float* __restrict__ kv,
    const float* __restrict__ agg, const float* __restrict__ norm2,
    const unsigned int* __restrict__ maxu,
    float* __restrict__ out_attn, float* __restrict__ out_ctx)
{
    __shared__ float e_s[512];
    __shared__ float red[8];
    __shared__ float zbc;
    __shared__ float ctx_part[4][128];

    const int b = blockIdx.x, t = threadIdx.x, lane = t & 63, w = t >> 6;

    const float v  = agg[(size_t)b*NN + t];
    const bool um  = mask[(size_t)b*NN + t] != 0.f;
    const float nrm = sqrtf(norm2[b]);
    const unsigned int u = maxu[b];
    const float M = __uint_as_float((u & 0x80000000u) ? (u & 0x7FFFFFFFu) : ~u);

    const float e = um ? expf((v - M) / nrm) : 0.f;
    e_s[t] = e;
    float z = e;
    #pragma unroll
    for (int off = 1; off <= 32; off <<= 1) z += __shfl_xor(z, off);
    if (lane == 0) red[w] = z;
    __syncthreads();
    if (t == 0) {
        float s = 0.f;
        #pragma unroll
        for (int i = 0; i < 8; i++) s += red[i];
        zbc = s;
    }
    __syncthreads();
    const float Z = zbc;
    out_attn[(size_t)b*NN + t] = e / Z;

    // context
    const int g = t >> 7, d = t & 127;
    float a = 0.f;
    for (int n = g; n < NN; n += 4)
        a += e_s[n] * kv[((size_t)b*NN + n)*ND + d];
    ctx_part[g][d] = a;
    __syncthreads();
    if (t < 128)
        out_ctx[(size_t)b*ND + t] =
            (ctx_part[0][t] + ctx_part[1][t] + ctx_part[2][t] + ctx_part[3][t]) / Z;
}

extern "C" void kernel_launch(void* const* d_in, const int* in_sizes, int n_in,
                              void* d_out, int out_size, void* d_ws, size_t ws_size,
                              hipStream_t stream)
{
    const float* aq   = (const float*)d_in[0];
    const float* mask = (const float*)d_in[1];
    const float* Wq   = (const float*)d_in[2];
    const float* bq   = (const float*)d_in[3];
    const float* Wk   = (const float*)d_in[4];
    const float* bk   = (const float*)d_in[5];

    float* ws = (float*)d_ws;
    float*          kv    = ws + KV_OFF;
    float*          qk    = ws + QK_OFF;
    float*          agg   = ws + AGG_OFF;
    unsigned short* Wt    = (unsigned short*)(ws + WT_OFF);
    float*          qsum  = ws + QSUM_OFF;
    float*          norm2 = ws + NORM2_OFF;
    unsigned int*   maxu  = (unsigned int*)(ws + MAXU_OFF);

    float* out_attn = (float*)d_out;
    float* out_ctx  = (float*)d_out + NB*NN;

    hipMemsetAsync(qsum, 0, (NB*ND + NB + NB)*sizeof(float), stream);
    conv_w<<<dim3(128), dim3(256), 0, stream>>>(Wq, Wk, Wt);
    proj_mfma<<<dim3(256), dim3(256), 0, stream>>>(aq, mask, Wt, bq, bk, kv, qk, qsum);
    agg_kernel<<<dim3(512), dim3(256), 0, stream>>>(mask, kv, qk, qsum, agg, norm2, maxu);
    attn_kernel<<<dim3(NB), dim3(512), 0, stream>>>(mask, kv, agg, norm2, maxu, out_attn, out_ctx);
}

// Round 3
// 109.821 us; speedup vs baseline: 1.5224x; 1.2694x over previous
//
#include <hip/hip_runtime.h>
#include <math.h>

#define NB 64
#define NN 512
#define ND 128

typedef __attribute__((ext_vector_type(8))) short short8;
typedef __attribute__((ext_vector_type(4))) float f32x4;

// workspace layout (floats)
#define KV_OFF    0
#define QK_OFF    (NB*NN*ND)
#define WT_OFF    (QK_OFF + NB*NN)         // 256*128 bf16 = 16384 floats
#define QSUM_OFF  (WT_OFF + 16384)

__device__ inline unsigned short f2bf(float x) {
    unsigned int u = __float_as_uint(x);
    return (unsigned short)((u + 0x7FFFu + ((u >> 16) & 1u)) >> 16);
}

// K0: Wt[c'][k] with c' = (matrix*128 + c); reads coalesced, writes scattered
// (posted stores, L2-backed; 128 KB total)
__global__ __launch_bounds__(256) void conv_w(
    const float* __restrict__ Wq, const float* __restrict__ Wk,
    unsigned short* __restrict__ Wt)
{
    const int idx = blockIdx.x * 256 + threadIdx.x;   // 0..32767
    const int m = idx >> 14, rem = idx & 16383;
    const int k = rem >> 7, c = rem & 127;
    const float v = m ? Wk[k*ND + c] : Wq[k*ND + c];
    Wt[(m*ND + c)*ND + k] = f2bf(v);
}

// K1: bf16 MFMA projection. Per block: 128 rows x (128 q-cols + 128 k-cols).
// Emits kv (k proj, fp32), qk[b,n] = q.k, qsum[b,d] += sum_n mask*q.
__global__ __launch_bounds__(256, 1) void proj_mfma(
    const float* __restrict__ aq, const float* __restrict__ mask,
    const unsigned short* __restrict__ Wt,
    const float* __restrict__ bq, const float* __restrict__ bk,
    float* __restrict__ kv, float* __restrict__ qk, float* __restrict__ qsum)
{
    __shared__ __align__(16) unsigned short a_lds[128][136];  // pitch 136: 2-way-free banks
    __shared__ float mask_lds[128];
    __shared__ float qk_part[4][128];

    const int b    = blockIdx.x >> 2;
    const int m0   = (blockIdx.x & 3) << 7;
    const int t    = threadIdx.x;
    const int w    = t >> 6, lane = t & 63;
    const int quad = lane >> 4, l16 = lane & 15;

    // stage aq tile fp32 -> bf16 LDS (coalesced float4 reads)
    {
        const float4* src = (const float4*)(aq + ((size_t)b*NN + m0)*ND);
        #pragma unroll
        for (int i = 0; i < 16; i++) {
            const int idx = t + 256*i;
            const int row = idx >> 5, c4 = idx & 31;
            const float4 v = src[idx];
            ushort4 o;
            o.x = f2bf(v.x); o.y = f2bf(v.y); o.z = f2bf(v.z); o.w = f2bf(v.w);
            *(ushort4*)&a_lds[row][c4*4] = o;
        }
        if (t < 128) mask_lds[t] = mask[b*NN + m0 + t];
    }

    // B fragments in registers: nt 0,1 = q cols [w*32, w*32+32); nt 2,3 = k cols same range
    short8 bfr[4][4];
    #pragma unroll
    for (int nt = 0; nt < 4; nt++) {
        const int col = (nt < 2) ? (w*32 + nt*16 + l16)
                                 : (ND + w*32 + (nt-2)*16 + l16);
        #pragma unroll
        for (int kc = 0; kc < 4; kc++)
            bfr[nt][kc] = *(const short8*)(Wt + col*ND + kc*32 + quad*8);
    }

    __syncthreads();

    f32x4 acc[8][4];
    #pragma unroll
    for (int m = 0; m < 8; m++)
        #pragma unroll
        for (int nt = 0; nt < 4; nt++)
            acc[m][nt] = (f32x4){0.f, 0.f, 0.f, 0.f};

    #pragma unroll
    for (int m = 0; m < 8; m++) {
        short8 afr[4];
        #pragma unroll
        for (int kc = 0; kc < 4; kc++)
            afr[kc] = *(const short8*)&a_lds[m*16 + l16][kc*32 + quad*8];
        #pragma unroll
        for (int nt = 0; nt < 4; nt++)
            #pragma unroll
            for (int kc = 0; kc < 4; kc++)
                acc[m][nt] = __builtin_amdgcn_mfma_f32_16x16x32_bf16(
                    afr[kc], bfr[nt][kc], acc[m][nt], 0, 0, 0);
    }

    // bias
    float bv[4];
    #pragma unroll
    for (int nt = 0; nt < 2; nt++) bv[nt] = bq[w*32 + nt*16 + l16];
    #pragma unroll
    for (int nt = 2; nt < 4; nt++) bv[nt] = bk[w*32 + (nt-2)*16 + l16];
    #pragma unroll
    for (int m = 0; m < 8; m++)
        #pragma unroll
        for (int nt = 0; nt < 4; nt++)
            #pragma unroll
            for (int r = 0; r < 4; r++)
                acc[m][nt][r] += bv[nt];

    // store k rows (C layout: row = m*16 + quad*4 + r, col = base + l16)
    #pragma unroll
    for (int m = 0; m < 8; m++)
        #pragma unroll
        for (int r = 0; r < 4; r++) {
            const size_t row = (size_t)b*NN + m0 + m*16 + quad*4 + r;
            kv[row*ND + w*32 + l16]      = acc[m][2][r];
            kv[row*ND + w*32 + 16 + l16] = acc[m][3][r];
        }

    // qk partial: sum over this wave's 32 d-cols, butterfly over the 16-lane col group
    #pragma unroll
    for (int m = 0; m < 8; m++) {
        float p[4];
        #pragma unroll
        for (int r = 0; r < 4; r++)
            p[r] = acc[m][0][r]*acc[m][2][r] + acc[m][1][r]*acc[m][3][r];
        #pragma unroll
        for (int off = 1; off <= 8; off <<= 1)
            #pragma unroll
            for (int r = 0; r < 4; r++)
                p[r] += __shfl_xor(p[r], off);
        if (l16 == 0)
            #pragma unroll
            for (int r = 0; r < 4; r++)
                qk_part[w][m*16 + quad*4 + r] = p[r];
    }

    // qsum partial: reduce over rows (mask per row), butterfly over quads
    {
        float s0 = 0.f, s1 = 0.f;
        #pragma unroll
        for (int m = 0; m < 8; m++)
            #pragma unroll
            for (int r = 0; r < 4; r++) {
                const float mk = mask_lds[m*16 + quad*4 + r];
                s0 += mk * acc[m][0][r];
                s1 += mk * acc[m][1][r];
            }
        s0 += __shfl_xor(s0, 16); s0 += __shfl_xor(s0, 32);
        s1 += __shfl_xor(s1, 16); s1 += __shfl_xor(s1, 32);
        if (quad == 0) {
            atomicAdd(&qsum[b*ND + w*32 + l16],      s0);
            atomicAdd(&qsum[b*ND + w*32 + 16 + l16], s1);
        }
    }

    __syncthreads();
    if (t < 128)
        qk[(size_t)b*NN + m0 + t] =
            qk_part[0][t] + qk_part[1][t] + qk_part[2][t] + qk_part[3][t];
}

// K2: fused agg + norm + softmax + context. Grid: b*4 + cg, 512 threads.
// Each block redundantly computes agg/softmax for its batch (in-block, no
// atomics), writes a 32-column context slice; cg==0 also writes attn.
__global__ __launch_bounds__(512) void fused_attn(
    const float* __restrict__ mask, const float* __restrict__ kv,
    const float* __restrict__ qk, const float* __restrict__ qsum,
    float* __restrict__ out_attn, float* __restrict__ out_ctx)
{
    __shared__ float qs[128];
    __shared__ float agg_s[512];          // then reused to hold e
    __shared__ float red[16];
    __shared__ float bc2[2];
    __shared__ float zred[8];
    __shared__ float zbc;
    __shared__ float ctx_part[16][32];

    const int b  = blockIdx.x >> 2;
    const int cg = blockIdx.x & 3;
    const int t = threadIdx.x, w = t >> 6, lane = t & 63;

    if (t < 128) qs[t] = qsum[b*ND + t];
    __syncthreads();
    const float q0 = qs[2*lane], q1 = qs[2*lane + 1];

    // Phase A: agg[n] for all 512 n; 8 waves x 64 rows, batches of 4
    for (int i0 = 0; i0 < 64; i0 += 4) {
        float p[4];
        #pragma unroll
        for (int r = 0; r < 4; r++) {
            const int n = w*64 + i0 + r;
            const float2 kvv = *(const float2*)(kv + ((size_t)b*NN + n)*ND + 2*lane);
            p[r] = kvv.x*q0 + kvv.y*q1;
        }
        #pragma unroll
        for (int off = 1; off <= 32; off <<= 1)
            #pragma unroll
            for (int r = 0; r < 4; r++) p[r] += __shfl_xor(p[r], off);
        if (lane == 0) {
            #pragma unroll
            for (int r = 0; r < 4; r++) {
                const int n = w*64 + i0 + r;
                agg_s[n] = mask[(size_t)b*NN + n] * (p[r] - qk[(size_t)b*NN + n]);
            }
        }
    }
    __syncthreads();

    // Phase B: norm2 + masked max over 512 rows (thread t owns row t)
    const float v  = agg_s[t];
    const bool um  = mask[(size_t)b*NN + t] != 0.f;
    float sq = v * v;
    float mx = um ? v : -3.0e38f;
    #pragma unroll
    for (int off = 1; off <= 32; off <<= 1) {
        sq += __shfl_xor(sq, off);
        mx = fmaxf(mx, __shfl_xor(mx, off));
    }
    if (lane == 0) { red[w] = sq; red[8 + w] = mx; }
    __syncthreads();
    if (t == 0) {
        float s = 0.f, m = -3.0e38f;
        #pragma unroll
        for (int i = 0; i < 8; i++) { s += red[i]; m = fmaxf(m, red[8 + i]); }
        bc2[0] = sqrtf(s);
        bc2[1] = m;
    }
    __syncthreads();
    const float nrm = bc2[0];
    const float M   = bc2[1];

    // Phase C: masked exp + Z
    const float e = um ? expf((v - M) / nrm) : 0.f;
    float z = e;
    #pragma unroll
    for (int off = 1; off <= 32; off <<= 1) z += __shfl_xor(z, off);
    if (lane == 0) zred[w] = z;
    agg_s[t] = e;                 // own slot only (was read by same thread)
    __syncthreads();
    if (t == 0) {
        float s = 0.f;
        #pragma unroll
        for (int i = 0; i < 8; i++) s += zred[i];
        zbc = s;
    }
    __syncthreads();
    const float Z = zbc;
    if (cg == 0) out_attn[(size_t)b*NN + t] = e / Z;

    // Phase D: context slice, cols [cg*32, cg*32+32)
    const int col = cg*32 + (t & 31);
    const int rg  = t >> 5;              // 16 row groups
    float a = 0.f;
    for (int n = rg; n < NN; n += 16)
        a += agg_s[n] * kv[((size_t)b*NN + n)*ND + col];
    ctx_part[rg][t & 31] = a;
    __syncthreads();
    if (t < 32) {
        float s = 0.f;
        #pragma unroll
        for (int i = 0; i < 16; i++) s += ctx_part[i][t];
        out_ctx[(size_t)b*ND + cg*32 + t] = s / Z;
    }
}

extern "C" void kernel_launch(void* const* d_in, const int* in_sizes, int n_in,
                              void* d_out, int out_size, void* d_ws, size_t ws_size,
                              hipStream_t stream)
{
    const float* aq   = (const float*)d_in[0];
    const float* mask = (const float*)d_in[1];
    const float* Wq   = (const float*)d_in[2];
    const float* bq   = (const float*)d_in[3];
    const float* Wk   = (const float*)d_in[4];
    const float* bk   = (const float*)d_in[5];

    float* ws = (float*)d_ws;
    float*          kv   = ws + KV_OFF;
    float*          qk   = ws + QK_OFF;
    unsigned short* Wt   = (unsigned short*)(ws + WT_OFF);
    float*          qsum = ws + QSUM_OFF;

    float* out_attn = (float*)d_out;
    float* out_ctx  = (float*)d_out + NB*NN;

    hipMemsetAsync(qsum, 0, NB*ND*sizeof(float), stream);
    conv_w<<<dim3(128), dim3(256), 0, stream>>>(Wq, Wk, Wt);
    proj_mfma<<<dim3(256), dim3(256), 0, stream>>>(aq, mask, Wt, bq, bk, kv, qk, qsum);
    fused_attn<<<dim3(256), dim3(512), 0, stream>>>(mask, kv, qk, qsum, out_attn, out_ctx);
}

// Round 4
// 104.371 us; speedup vs baseline: 1.6018x; 1.0522x over previous
//
#include <hip/hip_runtime.h>
#include <math.h>

#define NB 64
#define NN 512
#define ND 128

typedef __attribute__((ext_vector_type(8))) short short8;
typedef __attribute__((ext_vector_type(4))) float f32x4;

// workspace layout (floats)
#define KVB_OFF   0                         // kv bf16: NB*NN*ND ushorts = 2,097,152 floats
#define QK_OFF    (NB*NN*ND/2)
#define WT_OFF    (QK_OFF + NB*NN)          // 256*128 bf16 = 16384 floats
#define QSUMP_OFF (WT_OFF + 16384)          // qsum partials: NB*4*ND floats

__device__ inline unsigned short f2bf(float x) {
    unsigned int u = __float_as_uint(x);
    return (unsigned short)((u + 0x7FFFu + ((u >> 16) & 1u)) >> 16);
}
__device__ inline float bf2f(unsigned short u) {
    return __uint_as_float(((unsigned int)u) << 16);
}

// K0: Wt[c'][k] with c' = (matrix*128 + c); reads coalesced, writes scattered
__global__ __launch_bounds__(256) void conv_w(
    const float* __restrict__ Wq, const float* __restrict__ Wk,
    unsigned short* __restrict__ Wt)
{
    const int idx = blockIdx.x * 256 + threadIdx.x;   // 0..32767
    const int m = idx >> 14, rem = idx & 16383;
    const int k = rem >> 7, c = rem & 127;
    const float v = m ? Wk[k*ND + c] : Wq[k*ND + c];
    Wt[(m*ND + c)*ND + k] = f2bf(v);
}

// K1: bf16 MFMA projection. Per block: 128 rows x (128 q-cols + 128 k-cols).
// Emits kvb (k proj, bf16), qk[b,n] = q.k (fp32), qsum_part[b][chunk][d].
__global__ __launch_bounds__(256, 1) void proj_mfma(
    const float* __restrict__ aq, const float* __restrict__ mask,
    const unsigned short* __restrict__ Wt,
    const float* __restrict__ bq, const float* __restrict__ bk,
    unsigned short* __restrict__ kvb, float* __restrict__ qk,
    float* __restrict__ qsum_part)
{
    __shared__ __align__(16) unsigned short a_lds[128][136];  // pitch 136
    __shared__ float mask_lds[128];
    __shared__ float qk_part[4][128];

    const int b    = blockIdx.x >> 2;
    const int m0   = (blockIdx.x & 3) << 7;
    const int t    = threadIdx.x;
    const int w    = t >> 6, lane = t & 63;
    const int quad = lane >> 4, l16 = lane & 15;

    // stage aq tile fp32 -> bf16 LDS (coalesced float4 reads)
    {
        const float4* src = (const float4*)(aq + ((size_t)b*NN + m0)*ND);
        #pragma unroll
        for (int i = 0; i < 16; i++) {
            const int idx = t + 256*i;
            const int row = idx >> 5, c4 = idx & 31;
            const float4 v = src[idx];
            ushort4 o;
            o.x = f2bf(v.x); o.y = f2bf(v.y); o.z = f2bf(v.z); o.w = f2bf(v.w);
            *(ushort4*)&a_lds[row][c4*4] = o;
        }
        if (t < 128) mask_lds[t] = mask[b*NN + m0 + t];
    }

    // B fragments: nt 0,1 = q cols [w*32, w*32+32); nt 2,3 = k cols same range
    short8 bfr[4][4];
    #pragma unroll
    for (int nt = 0; nt < 4; nt++) {
        const int col = (nt < 2) ? (w*32 + nt*16 + l16)
                                 : (ND + w*32 + (nt-2)*16 + l16);
        #pragma unroll
        for (int kc = 0; kc < 4; kc++)
            bfr[nt][kc] = *(const short8*)(Wt + col*ND + kc*32 + quad*8);
    }

    __syncthreads();

    f32x4 acc[8][4];
    #pragma unroll
    for (int m = 0; m < 8; m++)
        #pragma unroll
        for (int nt = 0; nt < 4; nt++)
            acc[m][nt] = (f32x4){0.f, 0.f, 0.f, 0.f};

    #pragma unroll
    for (int m = 0; m < 8; m++) {
        short8 afr[4];
        #pragma unroll
        for (int kc = 0; kc < 4; kc++)
            afr[kc] = *(const short8*)&a_lds[m*16 + l16][kc*32 + quad*8];
        #pragma unroll
        for (int nt = 0; nt < 4; nt++)
            #pragma unroll
            for (int kc = 0; kc < 4; kc++)
                acc[m][nt] = __builtin_amdgcn_mfma_f32_16x16x32_bf16(
                    afr[kc], bfr[nt][kc], acc[m][nt], 0, 0, 0);
    }

    // bias
    float bv[4];
    #pragma unroll
    for (int nt = 0; nt < 2; nt++) bv[nt] = bq[w*32 + nt*16 + l16];
    #pragma unroll
    for (int nt = 2; nt < 4; nt++) bv[nt] = bk[w*32 + (nt-2)*16 + l16];
    #pragma unroll
    for (int m = 0; m < 8; m++)
        #pragma unroll
        for (int nt = 0; nt < 4; nt++)
            #pragma unroll
            for (int r = 0; r < 4; r++)
                acc[m][nt][r] += bv[nt];

    // store k rows as bf16 (C layout: row = m*16 + quad*4 + r, col = base + l16)
    #pragma unroll
    for (int m = 0; m < 8; m++)
        #pragma unroll
        for (int r = 0; r < 4; r++) {
            const size_t row = (size_t)b*NN + m0 + m*16 + quad*4 + r;
            kvb[row*ND + w*32 + l16]      = f2bf(acc[m][2][r]);
            kvb[row*ND + w*32 + 16 + l16] = f2bf(acc[m][3][r]);
        }

    // qk partial: q.k over this wave's 32 d-cols (full fp32 precision)
    #pragma unroll
    for (int m = 0; m < 8; m++) {
        float p[4];
        #pragma unroll
        for (int r = 0; r < 4; r++)
            p[r] = acc[m][0][r]*acc[m][2][r] + acc[m][1][r]*acc[m][3][r];
        #pragma unroll
        for (int off = 1; off <= 8; off <<= 1)
            #pragma unroll
            for (int r = 0; r < 4; r++)
                p[r] += __shfl_xor(p[r], off);
        if (l16 == 0)
            #pragma unroll
            for (int r = 0; r < 4; r++)
                qk_part[w][m*16 + quad*4 + r] = p[r];
    }

    // qsum partial over this block's 128 rows: wave w owns q-cols w*32..+31,
    // disjoint slots -> plain stores, no atomics, no memset
    {
        float s0 = 0.f, s1 = 0.f;
        #pragma unroll
        for (int m = 0; m < 8; m++)
            #pragma unroll
            for (int r = 0; r < 4; r++) {
                const float mk = mask_lds[m*16 + quad*4 + r];
                s0 += mk * acc[m][0][r];
                s1 += mk * acc[m][1][r];
            }
        s0 += __shfl_xor(s0, 16); s0 += __shfl_xor(s0, 32);
        s1 += __shfl_xor(s1, 16); s1 += __shfl_xor(s1, 32);
        if (quad == 0) {
            const int slot = (b*4 + (m0 >> 7)) * ND;
            qsum_part[slot + w*32 + l16]      = s0;
            qsum_part[slot + w*32 + 16 + l16] = s1;
        }
    }

    __syncthreads();
    if (t < 128)
        qk[(size_t)b*NN + m0 + t] =
            qk_part[0][t] + qk_part[1][t] + qk_part[2][t] + qk_part[3][t];
}

// K2: fused agg + norm + softmax + context. Grid: b*4 + cg, 512 threads.
__global__ __launch_bounds__(512) void fused_attn(
    const float* __restrict__ mask, const unsigned short* __restrict__ kvb,
    const float* __restrict__ qk, const float* __restrict__ qsum_part,
    float* __restrict__ out_attn, float* __restrict__ out_ctx)
{
    __shared__ float qs[128];
    __shared__ float mask_s[512];
    __shared__ float agg_s[512];          // then reused to hold e
    __shared__ float red[16];
    __shared__ float bc2[2];
    __shared__ float zred[8];
    __shared__ float zbc;
    __shared__ float ctx_part[16][32];

    const int b  = blockIdx.x >> 2;
    const int cg = blockIdx.x & 3;
    const int t = threadIdx.x, w = t >> 6, lane = t & 63;
    const size_t rowbase = (size_t)b * NN;

    if (t < 128)
        qs[t] = qsum_part[(b*4 + 0)*ND + t] + qsum_part[(b*4 + 1)*ND + t]
              + qsum_part[(b*4 + 2)*ND + t] + qsum_part[(b*4 + 3)*ND + t];
    mask_s[t] = mask[rowbase + t];
    __syncthreads();

    // per-lane qsum slice: lane handles d = h*4..h*4+3 (h = lane&31)
    const int h = lane & 31, half = lane >> 5;
    float qsf[4];
    #pragma unroll
    for (int j = 0; j < 4; j++) qsf[j] = qs[h*4 + j];

    // Phase A: agg[n] for all 512 n; each wave: 4 rows per iter (2 per half-wave)
    for (int i0 = 0; i0 < 64; i0 += 4) {
        const int na = w*64 + i0 + half;       // rows +0,+1
        const int nb2 = na + 2;                // rows +2,+3
        const ushort4 ka = *(const ushort4*)(kvb + (rowbase + na)*ND + h*4);
        const ushort4 kb = *(const ushort4*)(kvb + (rowbase + nb2)*ND + h*4);
        float p0 = bf2f(ka.x)*qsf[0] + bf2f(ka.y)*qsf[1]
                 + bf2f(ka.z)*qsf[2] + bf2f(ka.w)*qsf[3];
        float p1 = bf2f(kb.x)*qsf[0] + bf2f(kb.y)*qsf[1]
                 + bf2f(kb.z)*qsf[2] + bf2f(kb.w)*qsf[3];
        #pragma unroll
        for (int off = 1; off <= 16; off <<= 1) {
            p0 += __shfl_xor(p0, off);
            p1 += __shfl_xor(p1, off);
        }
        if (h == 0) {
            agg_s[na]  = mask_s[na]  * (p0 - qk[rowbase + na]);
            agg_s[nb2] = mask_s[nb2] * (p1 - qk[rowbase + nb2]);
        }
    }
    __syncthreads();

    // Phase B: norm2 + masked max over 512 rows (thread t owns row t)
    const float v  = agg_s[t];
    const bool um  = mask_s[t] != 0.f;
    float sq = v * v;
    float mx = um ? v : -3.0e38f;
    #pragma unroll
    for (int off = 1; off <= 32; off <<= 1) {
        sq += __shfl_xor(sq, off);
        mx = fmaxf(mx, __shfl_xor(mx, off));
    }
    if (lane == 0) { red[w] = sq; red[8 + w] = mx; }
    __syncthreads();
    if (t == 0) {
        float s = 0.f, m = -3.0e38f;
        #pragma unroll
        for (int i = 0; i < 8; i++) { s += red[i]; m = fmaxf(m, red[8 + i]); }
        bc2[0] = sqrtf(s);
        bc2[1] = m;
    }
    __syncthreads();
    const float nrm = bc2[0];
    const float M   = bc2[1];

    // Phase C: masked exp + Z
    const float e = um ? expf((v - M) / nrm) : 0.f;
    float z = e;
    #pragma unroll
    for (int off = 1; off <= 32; off <<= 1) z += __shfl_xor(z, off);
    if (lane == 0) zred[w] = z;
    agg_s[t] = e;                 // own slot only
    __syncthreads();
    if (t == 0) {
        float s = 0.f;
        #pragma unroll
        for (int i = 0; i < 8; i++) s += zred[i];
        zbc = s;
    }
    __syncthreads();
    const float Z = zbc;
    if (cg == 0) out_attn[rowbase + t] = e / Z;

    // Phase D: context slice, cols [cg*32, cg*32+32)
    const int col = cg*32 + (t & 31);
    const int rg  = t >> 5;              // 16 row groups
    float a = 0.f;
    for (int n = rg; n < NN; n += 16)
        a += agg_s[n] * bf2f(kvb[(rowbase + n)*ND + col]);
    ctx_part[rg][t & 31] = a;
    __syncthreads();
    if (t < 32) {
        float s = 0.f;
        #pragma unroll
        for (int i = 0; i < 16; i++) s += ctx_part[i][t];
        out_ctx[(size_t)b*ND + cg*32 + t] = s / Z;
    }
}

extern "C" void kernel_launch(void* const* d_in, const int* in_sizes, int n_in,
                              void* d_out, int out_size, void* d_ws, size_t ws_size,
                              hipStream_t stream)
{
    const float* aq   = (const float*)d_in[0];
    const float* mask = (const float*)d_in[1];
    const float* Wq   = (const float*)d_in[2];
    const float* bq   = (const float*)d_in[3];
    const float* Wk   = (const float*)d_in[4];
    const float* bk   = (const float*)d_in[5];

    float* ws = (float*)d_ws;
    unsigned short* kvb  = (unsigned short*)(ws + KVB_OFF);
    float*          qk   = ws + QK_OFF;
    unsigned short* Wt   = (unsigned short*)(ws + WT_OFF);
    float*          qsum_part = ws + QSUMP_OFF;

    float* out_attn = (float*)d_out;
    float* out_ctx  = (float*)d_out + NB*NN;

    conv_w<<<dim3(128), dim3(256), 0, stream>>>(Wq, Wk, Wt);
    proj_mfma<<<dim3(256), dim3(256), 0, stream>>>(aq, mask, Wt, bq, bk, kvb, qk, qsum_part);
    fused_attn<<<dim3(256), dim3(512), 0, stream>>>(mask, kvb, qk, qsum_part, out_attn, out_ctx);
}